// Round 7
// baseline (232.696 us; speedup 1.0000x reference)
//
#include <hip/hip_runtime.h>
#include <hip/hip_bf16.h>
#include <stdint.h>
#include <stddef.h>

// DCNv2 forward: B=4, H=W=96, C=256, F=256, K=9 (3x3, same, stride1, dil1), DG=1.
// R5/R8/R11: fusion failed 3x. Split pipeline kept for good.
// R7: chunk-XOR swizzle: bank conflicts 6.19M->0. R9: XCD swizzle (-5us).
// R10: 3-deep counted-vmcnt regressed (LDS 48KB occupancy cliff + FETCH +72%).
// R12: atomic-free k_omgemm + split prep: 222->213us. k_gemm still 67us @ 1.9TB/s,
//   MfmaUtil 27% -- neither pipe saturated.
// R13: k_gemm reads cols ONCE. Old grid (384,2) split N -> 340MB logical reads,
//   self-evicting L3 -> 87.6MB HBM fetch. New tile 64M x 256N (full F), 512thr
//   = 8 waves (2Mx4N, wave 32x64, acc[2][4]), LDS 2x20KB=40KB, grid 576 = 2.25blk/CU
//   x 8w = 4.5 waves/SIMD. XCD swizzle matches k_sample's px partition so each XCD
//   reads the cols slice it wrote (L3-hit). Predict FETCH<40MB, dur ~45us.

namespace {
constexpr int H  = 96, W = 96, C = 256, F = 256;
constexpr int HP = 98;            // padded spatial dim (1-px zero halo)
constexpr int NP = 4 * 96 * 96;   // 36864 output pixels
constexpr int KC = 9 * 256;       // 2304 = GEMM K

constexpr int NB_PAD  = 4 * HP * HP / 8;       // 4802 blocks, 8 px each
constexpr int NB_OMW  = 9 * 32;                // 288
constexpr int NB_WT   = (KC / 64) * (F / 64);  // 144
}

typedef __attribute__((ext_vector_type(8))) short bf16x8;
typedef __attribute__((ext_vector_type(4))) float floatx4;

__device__ __forceinline__ void load_lds16(const void* g, void* l) {
  __builtin_amdgcn_global_load_lds((const __attribute__((address_space(1))) void*)g,
                                   (__attribute__((address_space(3))) void*)l,
                                   16, 0, 0);
}

__device__ __forceinline__ uint32_t pk2(float lo, float hi) {   // v_cvt_pk_bf16_f32 (RNE)
  __hip_bfloat162 t = __float22bfloat162_rn(float2{lo, hi});
  return *reinterpret_cast<uint32_t*>(&t);
}

__device__ __forceinline__ void acc8(uint4 v, float w, float* a) {
  a[0] += w * __uint_as_float(v.x << 16); a[1] += w * __uint_as_float(v.x & 0xffff0000u);
  a[2] += w * __uint_as_float(v.y << 16); a[3] += w * __uint_as_float(v.y & 0xffff0000u);
  a[4] += w * __uint_as_float(v.z << 16); a[5] += w * __uint_as_float(v.z & 0xffff0000u);
  a[6] += w * __uint_as_float(v.w << 16); a[7] += w * __uint_as_float(v.w & 0xffff0000u);
}

// ---------------- k_pad: x fp32 -> xp bf16 with 1-px zero halo ----------------
__global__ __launch_bounds__(256) void k_pad(const float* __restrict__ x,
                                             uint4* __restrict__ xp4) {
  const int tid = threadIdx.x;
  const int sub = tid >> 5, cid = tid & 31;
  const int pp  = blockIdx.x * 8 + sub;
  const int b   = pp / (HP * HP);
  const int r   = pp % (HP * HP);
  const int y   = r / HP, xq = r % HP;
  uint4 o = {0u, 0u, 0u, 0u};
  if (y >= 1 && y <= H && xq >= 1 && xq <= W) {
    const float* src = x + ((size_t)((b * H + (y - 1)) * W + (xq - 1))) * C + cid * 8;
    const float4 v0 = *(const float4*)src;
    const float4 v1 = *(const float4*)(src + 4);
    o.x = pk2(v0.x, v0.y); o.y = pk2(v0.z, v0.w);
    o.z = pk2(v1.x, v1.y); o.w = pk2(v1.z, v1.w);
  }
  xp4[(size_t)pp * 32 + cid] = o;
}

// ---------------- k_wprep: omw repack + wt transpose ----------------
__global__ __launch_bounds__(256) void k_wprep(const float* __restrict__ omk,
                                               const float* __restrict__ kern,
                                               __hip_bfloat16* __restrict__ wom,
                                               __hip_bfloat16* __restrict__ wt) {
  __shared__ float t[64][65];
  const int bi = blockIdx.x, tid = threadIdx.x;

  if (bi < NB_OMW) {                       // ---- omw: [9*256][27] -> [32][2304] ----
    const int kk = bi / 32, oc = bi % 32;
    float v = (oc < 27) ? omk[(size_t)(kk * 256 + tid) * 27 + oc] : 0.f;
    wom[(size_t)oc * KC + kk * 256 + tid] = __float2bfloat16(v);
  } else {                                 // ---- wt: [KC][F] -> [F][KC] bf16 ----
    const int j   = bi - NB_OMW;
    const int kc0 = (j % (KC / 64)) * 64, f0 = (j / (KC / 64)) * 64;
    const int rr = tid >> 6, cc = tid & 63;
#pragma unroll
    for (int i = 0; i < 16; ++i)
      t[rr * 16 + i][cc] = kern[(size_t)(kc0 + rr * 16 + i) * F + f0 + cc];
    __syncthreads();
#pragma unroll
    for (int i = 0; i < 16; ++i) {
      const int frow = rr * 16 + i;
      wt[(size_t)(f0 + frow) * KC + kc0 + cc] = __float2bfloat16(t[cc][frow]);
    }
  }
}

// ---------------- k_omgemm: implicit-im2col MFMA GEMM, 64(M)x32(N), full K, no atomics ----
__global__ __launch_bounds__(256) void k_omgemm(const __hip_bfloat16* __restrict__ xp,
                                                const __hip_bfloat16* __restrict__ wom,
                                                float* __restrict__ pOm) {
  __shared__ __align__(16) char lds[12288];   // 2 x {A [64][32] 4KB, B [32][32] 2KB}
  const int tid  = threadIdx.x;
  const int xr   = blockIdx.x;
  const int xs   = (xr & 7) * 72 + (xr >> 3);     // XCD-contiguous over 576 tiles
  const int m0   = xs * 64;
  const int lane = tid & 63, wave = tid >> 6;
  const int quad = lane >> 4, l16 = lane & 15;

  const int kp  = (tid & 3) ^ ((tid >> 3) & 3);
  const int row = tid >> 2;
  const int p  = m0 + row;
  const int b  = p / (H * W);
  const int hw = p % (H * W);
  const int h  = hw / W, w = hw % W;
  const __hip_bfloat16* abase = xp + ((size_t)(b * HP + h) * HP + w) * C + kp * 8;
  const __hip_bfloat16* bbase = wom + (size_t)row * KC + kp * 8;   // valid for tid<128

  auto stage = [&](int buf, int k0) {
    const int kk = k0 >> 8, c0 = k0 & 255;
    const int aoff = ((kk / 3) * HP + (kk % 3)) * C + c0;
    char* base = &lds[buf * 6144];
    load_lds16(abase + aoff, base + tid * 16);
    if (tid < 128) load_lds16(bbase + k0, base + 4096 + tid * 16);
  };

  floatx4 acc[2];
  acc[0] = (floatx4){0.f, 0.f, 0.f, 0.f};
  acc[1] = (floatx4){0.f, 0.f, 0.f, 0.f};

  const int swq = (quad ^ ((l16 >> 1) & 3)) * 16;

  stage(0, 0);
  int cur = 0;
#pragma unroll 1
  for (int k0 = 0; k0 < KC; k0 += 32) {
    __syncthreads();                       // drains stage issued last iter (or prologue)
    if (k0 + 32 < KC) stage(cur ^ 1, k0 + 32);
    const char* base = &lds[cur * 6144];

    bf16x8 af = *(const bf16x8*)&base[(wave * 16 + l16) * 64 + swq];
    bf16x8 b0 = *(const bf16x8*)&base[4096 + (l16) * 64 + swq];
    bf16x8 b1 = *(const bf16x8*)&base[4096 + (16 + l16) * 64 + swq];
    acc[0] = __builtin_amdgcn_mfma_f32_16x16x32_bf16(af, b0, acc[0], 0, 0, 0);
    acc[1] = __builtin_amdgcn_mfma_f32_16x16x32_bf16(af, b1, acc[1], 0, 0, 0);
    cur ^= 1;
  }

#pragma unroll
  for (int nt = 0; nt < 2; ++nt) {
    const int gm = m0 + wave * 16 + quad * 4;
    const int gn = nt * 16 + l16;
#pragma unroll
    for (int r = 0; r < 4; ++r)
      pOm[(size_t)(gm + r) * 32 + gn] = acc[nt][r];
  }
}

// ---------------- k_sample: 8 px/block, 8 ch/thread via uint4 full-line gathers ----------------
__global__ __launch_bounds__(256) void k_sample(const uint4* __restrict__ xp4,
                                                const float* __restrict__ pOm,
                                                const float* __restrict__ om_bias,
                                                uint4* __restrict__ cols4) {
  __shared__ float2 s_ow[8][9][4];   // per (px,k,corner): {uint4-offset, weight*mask}

  const int tid = threadIdx.x;
  const int sub = tid >> 5, cid = tid & 31;     // px-in-block, 8-ch unit
  const int bs  = (blockIdx.x & 7) * 576 + (blockIdx.x >> 3);   // XCD-contiguous

  if (tid < 72) {                               // setup: 8 px x 9 k
    const int ps = tid / 9, k = tid % 9;
    const int p  = bs * 8 + ps;
    const int b  = p / (H * W);
    const int hw = p % (H * W);
    const int h = hw / W, w = hw % W;
    const float dy = om_bias[2 * k]     + pOm[(size_t)p * 32 + 2 * k];
    const float dx = om_bias[2 * k + 1] + pOm[(size_t)p * 32 + 2 * k + 1];
    const float mv = om_bias[18 + k]    + pOm[(size_t)p * 32 + 18 + k];
    const float m  = 2.f / (1.f + __expf(-mv));
    const float sy = (float)(h - 1 + k / 3) + dy;
    const float sx = (float)(w - 1 + k % 3) + dx;
    const float y0f = floorf(sy), x0f = floorf(sx);
    const float fy = sy - y0f, fx = sx - x0f;
    const int y0 = (int)y0f, x0 = (int)x0f;
#pragma unroll
    for (int c2 = 0; c2 < 4; ++c2) {
      const int dy2 = c2 >> 1, dx2 = c2 & 1;
      const int yi = y0 + dy2, xi = x0 + dx2;
      const bool valid = (yi >= 0) & (yi < H) & (xi >= 0) & (xi < W);
      const float wgt = valid ? (dy2 ? fy : 1.f - fy) * (dx2 ? fx : 1.f - fx) * m : 0.f;
      const int yc = min(max(yi + 1, 0), HP - 1);
      const int xc = min(max(xi + 1, 0), HP - 1);
      const int off = ((b * HP + yc) * HP + xc) * 32;   // uint4 units
      s_ow[ps][k][c2] = float2{__int_as_float(off), wgt};
    }
  }
  __syncthreads();

  const int p = bs * 8 + sub;
  uint4* __restrict__ ob = cols4 + (size_t)p * 288 + cid;   // KC bf16 = 288 uint4/row

#pragma unroll 1
  for (int k = 0; k < 9; ++k) {
    const float2 ow0 = s_ow[sub][k][0], ow1 = s_ow[sub][k][1];
    const float2 ow2 = s_ow[sub][k][2], ow3 = s_ow[sub][k][3];
    float a[8] = {0.f, 0.f, 0.f, 0.f, 0.f, 0.f, 0.f, 0.f};
    acc8(xp4[(size_t)__float_as_int(ow0.x) + cid], ow0.y, a);
    acc8(xp4[(size_t)__float_as_int(ow1.x) + cid], ow1.y, a);
    acc8(xp4[(size_t)__float_as_int(ow2.x) + cid], ow2.y, a);
    acc8(xp4[(size_t)__float_as_int(ow3.x) + cid], ow3.y, a);
    uint4 o;
    o.x = pk2(a[0], a[1]); o.y = pk2(a[2], a[3]);
    o.z = pk2(a[4], a[5]); o.w = pk2(a[6], a[7]);
    ob[k * 32] = o;
  }
}

// ---------------- k_gemm: 64(M) x 256(N=full F), cols read ONCE, 2-phase dbuf ----------------
// 512 thr = 8 waves (2M x 4N), wave tile 32x64, acc[2][4]. Grid 576 XCD-swizzled to
// match k_sample's px partition. LDS 2 x {A 4KB, B 16KB} = 40KB.
__global__ __launch_bounds__(512) void k_gemm(const __hip_bfloat16* __restrict__ A,
                                              const __hip_bfloat16* __restrict__ Bt,
                                              const float* __restrict__ bias,
                                              float* __restrict__ out) {
  __shared__ __align__(16) char lds[40960];

  const int tid  = threadIdx.x;
  const int xs   = (blockIdx.x & 7) * 72 + (blockIdx.x >> 3);   // XCD-contiguous
  const int m0   = xs * 64;
  const int lane = tid & 63, wave = tid >> 6;
  const int wm = wave >> 2, wn = wave & 3;    // 2M x 4N waves; wave tile 32M x 64N
  const int quad = lane >> 4, l16 = lane & 15;

  const int row = tid >> 2, kp = (tid & 3) ^ ((tid >> 3) & 3);
  const __hip_bfloat16* asrc = A  + (size_t)(m0 + row) * KC + kp * 8;   // tid<256
  const __hip_bfloat16* bsrc = Bt + (size_t)row * KC + kp * 8;          // rows 0..127
  const __hip_bfloat16* bsrc1 = bsrc + (size_t)128 * KC;                // rows 128..255

  auto stage = [&](int buf, int k0) {
    char* base = &lds[buf * 20480];
    if (tid < 256) load_lds16(asrc + k0, base + tid * 16);
    load_lds16(bsrc  + k0, base + 4096 + tid * 16);
    load_lds16(bsrc1 + k0, base + 12288 + tid * 16);
  };

  floatx4 acc[2][4];
#pragma unroll
  for (int i = 0; i < 2; ++i)
#pragma unroll
    for (int j = 0; j < 4; ++j) acc[i][j] = (floatx4){0.f, 0.f, 0.f, 0.f};

  const int swq = (quad ^ ((l16 >> 1) & 3)) * 16;

  stage(0, 0);
  int cur = 0;
#pragma unroll 1
  for (int k0 = 0; k0 < KC; k0 += 32) {
    __syncthreads();                       // drains stage issued last iter (or prologue)
    if (k0 + 32 < KC) stage(cur ^ 1, k0 + 32);
    const char* base = &lds[cur * 20480];

    bf16x8 af[2], bfr[4];
#pragma unroll
    for (int mt = 0; mt < 2; ++mt)
      af[mt] = *(const bf16x8*)&base[(wm * 32 + mt * 16 + l16) * 64 + swq];
#pragma unroll
    for (int nt = 0; nt < 4; ++nt)
      bfr[nt] = *(const bf16x8*)&base[4096 + (wn * 64 + nt * 16 + l16) * 64 + swq];
#pragma unroll
    for (int mt = 0; mt < 2; ++mt)
#pragma unroll
      for (int nt = 0; nt < 4; ++nt)
        acc[mt][nt] = __builtin_amdgcn_mfma_f32_16x16x32_bf16(af[mt], bfr[nt], acc[mt][nt], 0, 0, 0);
    cur ^= 1;
  }

#pragma unroll
  for (int mt = 0; mt < 2; ++mt) {
#pragma unroll
    for (int nt = 0; nt < 4; ++nt) {
      const int gm = m0 + wm * 32 + mt * 16 + quad * 4;
      const int gn = wn * 64 + nt * 16 + l16;
      const float bs = bias[gn];
#pragma unroll
      for (int r = 0; r < 4; ++r)
        out[(size_t)(gm + r) * F + gn] = acc[mt][nt][r] + bs;
    }
  }
}

extern "C" void kernel_launch(void* const* d_in, const int* in_sizes, int n_in,
                              void* d_out, int out_size, void* d_ws, size_t ws_size,
                              hipStream_t stream) {
  const float* x    = (const float*)d_in[0];   // [4,96,96,256]
  const float* omk  = (const float*)d_in[1];   // [3,3,256,27]
  const float* omb  = (const float*)d_in[2];   // [27]
  const float* kern = (const float*)d_in[3];   // [2304,256]
  const float* bias = (const float*)d_in[4];   // [256]
  float* out = (float*)d_out;                  // [4,96,96,256]

  char* ws = (char*)d_ws;
  size_t off = 0;
  __hip_bfloat16* wt   = (__hip_bfloat16*)(ws + off); off += (size_t)F * KC * 2;           // 1,179,648
  __hip_bfloat16* xp   = (__hip_bfloat16*)(ws + off); off += (size_t)4 * HP * HP * C * 2;  // 19,668,992
  __hip_bfloat16* wom  = (__hip_bfloat16*)(ws + off); off += (size_t)32 * KC * 2;          // 147,456
  float*          pOm  = (float*)(ws + off);          off += (size_t)NP * 32 * 4;          // 4,718,592
  __hip_bfloat16* cols = (__hip_bfloat16*)(ws + off);                                      // 169,869,312

  k_pad   <<<dim3(NB_PAD),         256, 0, stream>>>(x, (uint4*)xp);
  k_wprep <<<dim3(NB_OMW + NB_WT), 256, 0, stream>>>(omk, kern, wom, wt);
  k_omgemm<<<dim3(576),            256, 0, stream>>>(xp, wom, pOm);
  k_sample<<<dim3(NP / 8),         256, 0, stream>>>((const uint4*)xp, pOm, omb, (uint4*)cols);
  k_gemm  <<<dim3(576),            512, 0, stream>>>(cols, wt, bias, out);
}